// Round 1
// baseline (63.076 us; speedup 1.0000x reference)
//
#include <hip/hip_runtime.h>

// Problem constants (from reference): B=8192, N=34, D=16
#define BB 8192
#define NN 34
#define DD 16
#define PP 594   // sum_{i=0}^{32} (34-i) = 34*35/2 - 1

// Compile-time pair table: p -> (i<<8)|j, i in [0,N-2], j in [i,N-1]
struct PairTab { unsigned short v[PP]; };
constexpr PairTab make_tab() {
    PairTab t{};
    int p = 0;
    for (int i = 0; i < NN - 1; ++i)
        for (int j = i; j < NN; ++j)
            t.v[p++] = (unsigned short)((i << 8) | j);
    return t;
}
__device__ __constant__ PairTab c_tab = make_tab();

__global__ __launch_bounds__(256)
void BiInteraction_38577396253196_kernel(const float* __restrict__ x,
                                         const float* __restrict__ W,
                                         float* __restrict__ out)
{
    __shared__ float xs[NN * DD];   // 544 floats: x[b]
    __shared__ float ws[DD * DD];   // 256 floats: W
    __shared__ float ps[NN * DD];   // 544 floats: proj[b] = x[b] @ W

    const int b = blockIdx.x;
    const int t = threadIdx.x;

    // Stage x[b] (136 float4) and W (64 float4) into LDS.
    const float4* xg = (const float4*)(x + (size_t)b * (NN * DD));
    if (t < 136) ((float4*)xs)[t] = xg[t];
    if (t >= 192) ((float4*)ws)[t - 192] = ((const float4*)W)[t - 192];
    __syncthreads();

    // proj[n][e] = sum_d x[n][d] * W[d][e]   (544 outputs, 16 FMAs each)
    for (int q = t; q < NN * DD; q += 256) {
        const int n = q >> 4, e = q & 15;
        float acc = 0.f;
#pragma unroll
        for (int d = 0; d < DD; ++d)
            acc = fmaf(xs[n * DD + d], ws[d * DD + e], acc);
        ps[q] = acc;
    }
    __syncthreads();

    // out[b, p*16 + d] = proj[ii[p]][d] * x[jj[p]][d]; float4-vectorized,
    // flat index strided by thread -> coalesced 16B/lane stores.
    float4* og = (float4*)(out + (size_t)b * (PP * DD));
    const float4* psv = (const float4*)ps;
    const float4* xsv = (const float4*)xs;
    for (int k4 = t; k4 < PP * 4; k4 += 256) {
        const int p = k4 >> 2, d4 = k4 & 3;
        const unsigned pr = c_tab.v[p];
        const int i = pr >> 8, j = pr & 255;
        const float4 a  = psv[i * 4 + d4];
        const float4 xb = xsv[j * 4 + d4];
        float4 r;
        r.x = a.x * xb.x; r.y = a.y * xb.y; r.z = a.z * xb.z; r.w = a.w * xb.w;
        og[k4] = r;
    }
}

extern "C" void kernel_launch(void* const* d_in, const int* in_sizes, int n_in,
                              void* d_out, int out_size, void* d_ws, size_t ws_size,
                              hipStream_t stream) {
    const float* x = (const float*)d_in[0];   // [B, N, D] fp32
    const float* W = (const float*)d_in[1];   // [D, D] fp32
    float* out = (float*)d_out;               // [B, P*D] fp32

    BiInteraction_38577396253196_kernel<<<BB, 256, 0, stream>>>(x, W, out);
}